// Round 17
// baseline (164.494 us; speedup 1.0000x reference)
//
#include <hip/hip_runtime.h>
#include <hip/hip_bf16.h>
#include <hip/hip_fp16.h>

typedef __attribute__((ext_vector_type(4))) float f32x4;
typedef _Float16 h8 __attribute__((ext_vector_type(8)));
typedef int i32x4 __attribute__((ext_vector_type(4)));
typedef _Float16 h2 __attribute__((ext_vector_type(2)));

static __device__ __forceinline__ h2 ih2(int x) { return __builtin_bit_cast(h2, x); }
static __device__ __forceinline__ unsigned pkrtz(float lo, float hi) {
  return __builtin_bit_cast(unsigned, __builtin_amdgcn_cvt_pkrtz(lo, hi));
}
// inline-asm packed f16 ops
static __device__ __forceinline__ int pkmin(int x, int y) {
  int d; asm("v_pk_min_f16 %0, %1, %2" : "=v"(d) : "v"(x), "v"(y)); return d;
}
static __device__ __forceinline__ int pkmax(int x, int y) {
  int d; asm("v_pk_max_f16 %0, %1, %2" : "=v"(d) : "v"(x), "v"(y)); return d;
}
static __device__ __forceinline__ int pkadd(int x, int y) {
  int d; asm("v_pk_add_f16 %0, %1, %2" : "=v"(d) : "v"(x), "v"(y)); return d;
}

// Problem constants: B=32, L=64, C=128, D=512, O=256, L2=4096

// ------ K1 (fused prep): u,v = f16(x@w1 split + b1); w2t; pwt ------------
__global__ __launch_bounds__(256) void k_prep(const float* __restrict__ x,
                                              const float* __restrict__ w1,
                                              const float* __restrict__ b1,
                                              const float* __restrict__ w2,
                                              const float* __restrict__ pw,
                                              _Float16* __restrict__ u,
                                              _Float16* __restrict__ v,
                                              _Float16* __restrict__ w2t,
                                              float* __restrict__ pwt) {
  __shared__ float xs[8 * 128];
  int bid = blockIdx.x;
  int t = threadIdx.x;
  if (bid < 256) {
    int r0 = bid * 8;
    ((float4*)xs)[t] = ((const float4*)(x + (size_t)r0 * 128))[t];
    __syncthreads();
    int d1 = t, d2 = t + 256;
    float au0[8], au1[8], av0[8], av1[8];
    float bb1 = b1[d1], bb2 = b1[d2];
#pragma unroll
    for (int r = 0; r < 8; ++r) { au0[r] = bb1; au1[r] = bb2; av0[r] = 0.f; av1[r] = 0.f; }
#pragma unroll 4
    for (int c = 0; c < 128; ++c) {
      float wu1 = w1[c * 512 + d1];
      float wu2 = w1[c * 512 + d2];
      float wv1 = w1[(c + 128) * 512 + d1];
      float wv2 = w1[(c + 128) * 512 + d2];
#pragma unroll
      for (int r = 0; r < 8; ++r) {
        float xv = xs[r * 128 + c];
        au0[r] = fmaf(xv, wu1, au0[r]);
        au1[r] = fmaf(xv, wu2, au1[r]);
        av0[r] = fmaf(xv, wv1, av0[r]);
        av1[r] = fmaf(xv, wv2, av1[r]);
      }
    }
#pragma unroll
    for (int r = 0; r < 8; ++r) {
      u[(size_t)(r0 + r) * 512 + d1] = (_Float16)au0[r];
      u[(size_t)(r0 + r) * 512 + d2] = (_Float16)au1[r];
      v[(size_t)(r0 + r) * 512 + d1] = (_Float16)av0[r];
      v[(size_t)(r0 + r) * 512 + d2] = (_Float16)av1[r];
    }
  } else if (bid < 512) {
    int n = bid - 256;
    w2t[(size_t)n * 512 + t]       = (_Float16)w2[(size_t)t * 256 + n];
    w2t[(size_t)n * 512 + t + 256] = (_Float16)w2[(size_t)(t + 256) * 256 + n];
  } else {
    int o = bid - 512;
#pragma unroll
    for (int it = 0; it < 16; ++it) {
      int l = it * 256 + t;
      pwt[(size_t)o * 4096 + l] = pw[(size_t)l * 256 + o];
    }
  }
}

// ---- K4: register-built h = relu(u_i + v_j) -> f16 MFMA -> f16 y^T -----
__global__ __launch_bounds__(256, 2) void k_gemm(const _Float16* __restrict__ u,
                                                 const _Float16* __restrict__ v,
                                                 const _Float16* __restrict__ w2t,
                                                 const float* __restrict__ b2,
                                                 unsigned short* __restrict__ yt) {
  __shared__ char vl[64 * 1024];  // 64 rows x 512 f16, XOR-swizzled
  __shared__ char ulm[4 * 1024];  // 4 u-rows x 512 f16
  int t = threadIdx.x;
  int n0 = blockIdx.x;                     // 512 blocks
  int bid = (n0 & 7) * 64 + (n0 >> 3);     // XCD-bijective: same-b same XCD
  int b = bid >> 4, ig = bid & 15;
  {
    const char* vsrc = (const char*)(v + (size_t)b * 64 * 512);
#pragma unroll
    for (int it = 0; it < 16; ++it) {
      int f = it * 4096 + t * 16;
      uint4 d = *(const uint4*)(vsrc + f);
      int row = f >> 10;
      *(uint4*)(vl + (f ^ ((row & 7) << 4))) = d;
    }
    const char* usrc = (const char*)(u + (size_t)(b * 64 + ig * 4) * 512);
    int f = t * 16;
    *(uint4*)(ulm + f) = *(const uint4*)(usrc + f);
  }
  __syncthreads();
  int w = t >> 6, l = t & 63, lr = l & 15, lg = l >> 4;
  const _Float16* bptr[4];
  float bias[4];
#pragma unroll
  for (int ni = 0; ni < 4; ++ni) {
    int col = w * 64 + ni * 16 + lr;
    bptr[ni] = w2t + (size_t)col * 512 + lg * 8;
    bias[ni] = b2[col];
  }
#pragma unroll 1
  for (int ih = 0; ih < 2; ++ih) {  // i-pairs: i = ig*4 + ih*2 + {0,1}
    f32x4 acc[2][4][4];
#pragma unroll
    for (int ip = 0; ip < 2; ++ip)
#pragma unroll
      for (int mi = 0; mi < 4; ++mi)
#pragma unroll
        for (int ni = 0; ni < 4; ++ni) {
          float bv = bias[ni];
          f32x4 ci = {bv, bv, bv, bv};
          acc[ip][mi][ni] = ci;
        }
#pragma unroll 2
    for (int kk = 0; kk < 16; ++kk) {
      h8 bfv[4];
#pragma unroll
      for (int ni = 0; ni < 4; ++ni) bfv[ni] = *(const h8*)(bptr[ni] + kk * 32);
      i32x4 vf[4];
#pragma unroll
      for (int mi = 0; mi < 4; ++mi) {
        int row = mi * 16 + lr;
        int fb = row * 1024 + kk * 64 + lg * 16;
        vf[mi] = *(const i32x4*)(vl + (fb ^ ((row & 7) << 4)));
      }
#pragma unroll
      for (int ip = 0; ip < 2; ++ip) {
        i32x4 uf = *(const i32x4*)(ulm + (ih * 2 + ip) * 1024 + kk * 64 + lg * 16);
#pragma unroll
        for (int mi = 0; mi < 4; ++mi) {
          i32x4 aw;
#pragma unroll
          for (int q = 0; q < 4; ++q) aw[q] = pkmax(pkadd(uf[q], vf[mi][q]), 0);
          h8 af = __builtin_bit_cast(h8, aw);
#pragma unroll
          for (int ni = 0; ni < 4; ++ni)
            acc[ip][mi][ni] =
                __builtin_amdgcn_mfma_f32_16x16x32_f16(af, bfv[ni], acc[ip][mi][ni], 0, 0, 0);
        }
      }
    }
#pragma unroll
    for (int ip = 0; ip < 2; ++ip) {
      int i = ig * 4 + ih * 2 + ip;
#pragma unroll
      for (int ni = 0; ni < 4; ++ni) {
        int col = w * 64 + ni * 16 + lr;
        unsigned short* colbase = yt + (size_t)(b * 256 + col) * 4096 + (size_t)i * 64;
#pragma unroll
        for (int mi = 0; mi < 4; ++mi) {
          f32x4 vv = acc[ip][mi][ni];
          uint2 st;
          st.x = pkrtz(vv[0], vv[1]);
          st.y = pkrtz(vv[2], vv[3]);
          *(uint2*)(colbase + mi * 16 + lg * 4) = st;
        }
      }
    }
  }
}

// -- K5: E=64 single-wave sort, LOOP-COMPRESSED merge stages (I$-fit) ----
// op bodies (x,y,e are literal element numbers)
#define CEP(x, y, C) { int lo_ = pkmin(a##x, a##y); int hi_ = pkmax(a##x, a##y); a##x = lo_; a##y = hi_; }
#define KB(e, C) { int r_ = __builtin_amdgcn_ds_bpermute(pa_, a##e); int mn_ = pkmin(a##e, r_); int mx_ = pkmax(a##e, r_); a##e = km_ ? mn_ : mx_; }
#define KFB(x, y, C) { int r0_ = __builtin_amdgcn_ds_bpermute(pa_, a##y); int r1_ = __builtin_amdgcn_ds_bpermute(pa_, a##x); int mn0_ = pkmin(a##x, r0_); int mx0_ = pkmax(a##x, r0_); int mn1_ = pkmin(a##y, r1_); int mx1_ = pkmax(a##y, r1_); a##x = km_ ? mn0_ : mx0_; a##y = km_ ? mn1_ : mx1_; }

// element / pair lists
#define L64(F,C) F(0,C)F(1,C)F(2,C)F(3,C)F(4,C)F(5,C)F(6,C)F(7,C)F(8,C)F(9,C)F(10,C)F(11,C)F(12,C)F(13,C)F(14,C)F(15,C)F(16,C)F(17,C)F(18,C)F(19,C)F(20,C)F(21,C)F(22,C)F(23,C)F(24,C)F(25,C)F(26,C)F(27,C)F(28,C)F(29,C)F(30,C)F(31,C)F(32,C)F(33,C)F(34,C)F(35,C)F(36,C)F(37,C)F(38,C)F(39,C)F(40,C)F(41,C)F(42,C)F(43,C)F(44,C)F(45,C)F(46,C)F(47,C)F(48,C)F(49,C)F(50,C)F(51,C)F(52,C)F(53,C)F(54,C)F(55,C)F(56,C)F(57,C)F(58,C)F(59,C)F(60,C)F(61,C)F(62,C)F(63,C)
#define P_M1(F,C) F(0,1,C)F(2,3,C)F(4,5,C)F(6,7,C)F(8,9,C)F(10,11,C)F(12,13,C)F(14,15,C)F(16,17,C)F(18,19,C)F(20,21,C)F(22,23,C)F(24,25,C)F(26,27,C)F(28,29,C)F(30,31,C)F(32,33,C)F(34,35,C)F(36,37,C)F(38,39,C)F(40,41,C)F(42,43,C)F(44,45,C)F(46,47,C)F(48,49,C)F(50,51,C)F(52,53,C)F(54,55,C)F(56,57,C)F(58,59,C)F(60,61,C)F(62,63,C)
#define P_M2(F,C) F(0,2,C)F(1,3,C)F(4,6,C)F(5,7,C)F(8,10,C)F(9,11,C)F(12,14,C)F(13,15,C)F(16,18,C)F(17,19,C)F(20,22,C)F(21,23,C)F(24,26,C)F(25,27,C)F(28,30,C)F(29,31,C)F(32,34,C)F(33,35,C)F(36,38,C)F(37,39,C)F(40,42,C)F(41,43,C)F(44,46,C)F(45,47,C)F(48,50,C)F(49,51,C)F(52,54,C)F(53,55,C)F(56,58,C)F(57,59,C)F(60,62,C)F(61,63,C)
#define P_M3(F,C) F(0,3,C)F(1,2,C)F(4,7,C)F(5,6,C)F(8,11,C)F(9,10,C)F(12,15,C)F(13,14,C)F(16,19,C)F(17,18,C)F(20,23,C)F(21,22,C)F(24,27,C)F(25,26,C)F(28,31,C)F(29,30,C)F(32,35,C)F(33,34,C)F(36,39,C)F(37,38,C)F(40,43,C)F(41,42,C)F(44,47,C)F(45,46,C)F(48,51,C)F(49,50,C)F(52,55,C)F(53,54,C)F(56,59,C)F(57,58,C)F(60,63,C)F(61,62,C)
#define P_M4(F,C) F(0,4,C)F(1,5,C)F(2,6,C)F(3,7,C)F(8,12,C)F(9,13,C)F(10,14,C)F(11,15,C)F(16,20,C)F(17,21,C)F(18,22,C)F(19,23,C)F(24,28,C)F(25,29,C)F(26,30,C)F(27,31,C)F(32,36,C)F(33,37,C)F(34,38,C)F(35,39,C)F(40,44,C)F(41,45,C)F(42,46,C)F(43,47,C)F(48,52,C)F(49,53,C)F(50,54,C)F(51,55,C)F(56,60,C)F(57,61,C)F(58,62,C)F(59,63,C)
#define P_M7(F,C) F(0,7,C)F(1,6,C)F(2,5,C)F(3,4,C)F(8,15,C)F(9,14,C)F(10,13,C)F(11,12,C)F(16,23,C)F(17,22,C)F(18,21,C)F(19,20,C)F(24,31,C)F(25,30,C)F(26,29,C)F(27,28,C)F(32,39,C)F(33,38,C)F(34,37,C)F(35,36,C)F(40,47,C)F(41,46,C)F(42,45,C)F(43,44,C)F(48,55,C)F(49,54,C)F(50,53,C)F(51,52,C)F(56,63,C)F(57,62,C)F(58,61,C)F(59,60,C)
#define P_M8(F,C) F(0,8,C)F(1,9,C)F(2,10,C)F(3,11,C)F(4,12,C)F(5,13,C)F(6,14,C)F(7,15,C)F(16,24,C)F(17,25,C)F(18,26,C)F(19,27,C)F(20,28,C)F(21,29,C)F(22,30,C)F(23,31,C)F(32,40,C)F(33,41,C)F(34,42,C)F(35,43,C)F(36,44,C)F(37,45,C)F(38,46,C)F(39,47,C)F(48,56,C)F(49,57,C)F(50,58,C)F(51,59,C)F(52,60,C)F(53,61,C)F(54,62,C)F(55,63,C)
#define P_M15(F,C) F(0,15,C)F(1,14,C)F(2,13,C)F(3,12,C)F(4,11,C)F(5,10,C)F(6,9,C)F(7,8,C)F(16,31,C)F(17,30,C)F(18,29,C)F(19,28,C)F(20,27,C)F(21,26,C)F(22,25,C)F(23,24,C)F(32,47,C)F(33,46,C)F(34,45,C)F(35,44,C)F(36,43,C)F(37,42,C)F(38,41,C)F(39,40,C)F(48,63,C)F(49,62,C)F(50,61,C)F(51,60,C)F(52,59,C)F(53,58,C)F(54,57,C)F(55,56,C)
#define P_M16(F,C) F(0,16,C)F(1,17,C)F(2,18,C)F(3,19,C)F(4,20,C)F(5,21,C)F(6,22,C)F(7,23,C)F(8,24,C)F(9,25,C)F(10,26,C)F(11,27,C)F(12,28,C)F(13,29,C)F(14,30,C)F(15,31,C)F(32,48,C)F(33,49,C)F(34,50,C)F(35,51,C)F(36,52,C)F(37,53,C)F(38,54,C)F(39,55,C)F(40,56,C)F(41,57,C)F(42,58,C)F(43,59,C)F(44,60,C)F(45,61,C)F(46,62,C)F(47,63,C)
#define P_M31(F,C) F(0,31,C)F(1,30,C)F(2,29,C)F(3,28,C)F(4,27,C)F(5,26,C)F(6,25,C)F(7,24,C)F(8,23,C)F(9,22,C)F(10,21,C)F(11,20,C)F(12,19,C)F(13,18,C)F(14,17,C)F(15,16,C)F(32,63,C)F(33,62,C)F(34,61,C)F(35,60,C)F(36,59,C)F(37,58,C)F(38,57,C)F(39,56,C)F(40,55,C)F(41,54,C)F(42,53,C)F(43,52,C)F(44,51,C)F(45,50,C)F(46,49,C)F(47,48,C)
#define P_M32(F,C) F(0,32,C)F(1,33,C)F(2,34,C)F(3,35,C)F(4,36,C)F(5,37,C)F(6,38,C)F(7,39,C)F(8,40,C)F(9,41,C)F(10,42,C)F(11,43,C)F(12,44,C)F(13,45,C)F(14,46,C)F(15,47,C)F(16,48,C)F(17,49,C)F(18,50,C)F(19,51,C)F(20,52,C)F(21,53,C)F(22,54,C)F(23,55,C)F(24,56,C)F(25,57,C)F(26,58,C)F(27,59,C)F(28,60,C)F(29,61,C)F(30,62,C)F(31,63,C)
#define P_M63(F,C) F(0,63,C)F(1,62,C)F(2,61,C)F(3,60,C)F(4,59,C)F(5,58,C)F(6,57,C)F(7,56,C)F(8,55,C)F(9,54,C)F(10,53,C)F(11,52,C)F(12,51,C)F(13,50,C)F(14,49,C)F(15,48,C)F(16,47,C)F(17,46,C)F(18,45,C)F(19,44,C)F(20,43,C)F(21,42,C)F(22,41,C)F(23,40,C)F(24,39,C)F(25,38,C)F(26,37,C)F(27,36,C)F(28,35,C)F(29,34,C)F(30,33,C)F(31,32,C)

#define CLEAN6 P_M32(CEP,0) P_M16(CEP,0) P_M8(CEP,0) P_M4(CEP,0) P_M2(CEP,0) P_M1(CEP,0)

#define LOADQ(q,E0,E1,E2,E3,E4,E5,E6,E7) { uint4 x0_ = c0[q], x1_ = c1[q]; \
  a##E0 = (int)((x0_.x & 0xffffu) | (x1_.x << 16)); a##E1 = (int)((x0_.x >> 16) | (x1_.x & 0xffff0000u)); \
  a##E2 = (int)((x0_.y & 0xffffu) | (x1_.y << 16)); a##E3 = (int)((x0_.y >> 16) | (x1_.y & 0xffff0000u)); \
  a##E4 = (int)((x0_.z & 0xffffu) | (x1_.z << 16)); a##E5 = (int)((x0_.z >> 16) | (x1_.z & 0xffff0000u)); \
  a##E6 = (int)((x0_.w & 0xffffu) | (x1_.w << 16)); a##E7 = (int)((x0_.w >> 16) | (x1_.w & 0xffff0000u)); }

#define POOLQ(q,E0,E1,E2,E3) { float4 w0_ = pw0[q], w1_ = pw1[q]; h2 v_; \
  v_ = ih2(a##E0); s0 = fmaf((float)v_[0], w0_.x, s0); s1 = fmaf((float)v_[1], w1_.x, s1); \
  v_ = ih2(a##E1); s0 = fmaf((float)v_[0], w0_.y, s0); s1 = fmaf((float)v_[1], w1_.y, s1); \
  v_ = ih2(a##E2); s0 = fmaf((float)v_[0], w0_.z, s0); s1 = fmaf((float)v_[1], w1_.z, s1); \
  v_ = ih2(a##E3); s0 = fmaf((float)v_[0], w0_.w, s0); s1 = fmaf((float)v_[1], w1_.w, s1); }

__global__ __launch_bounds__(64, 2) void k_sortpool(const unsigned short* __restrict__ yt,
                                                    const float* __restrict__ pwt,
                                                    float* __restrict__ out) {
  int t = threadIdx.x;  // lane 0..63 (one wave per block)
  int b = blockIdx.x >> 7, p = blockIdx.x & 127;
  int o0 = p * 2, o1 = o0 + 1;
  const uint4* c0 = (const uint4*)(yt + (size_t)(b * 256 + o0) * 4096 + t * 64);
  const uint4* c1 = (const uint4*)(yt + (size_t)(b * 256 + o1) * 4096 + t * 64);
  int a0,a1,a2,a3,a4,a5,a6,a7,a8,a9,a10,a11,a12,a13,a14,a15,
      a16,a17,a18,a19,a20,a21,a22,a23,a24,a25,a26,a27,a28,a29,a30,a31,
      a32,a33,a34,a35,a36,a37,a38,a39,a40,a41,a42,a43,a44,a45,a46,a47,
      a48,a49,a50,a51,a52,a53,a54,a55,a56,a57,a58,a59,a60,a61,a62,a63;
  LOADQ(0, 0,1,2,3,4,5,6,7)
  LOADQ(1, 8,9,10,11,12,13,14,15)
  LOADQ(2, 16,17,18,19,20,21,22,23)
  LOADQ(3, 24,25,26,27,28,29,30,31)
  LOADQ(4, 32,33,34,35,36,37,38,39)
  LOADQ(5, 40,41,42,43,44,45,46,47)
  LOADQ(6, 48,49,50,51,52,53,54,55)
  LOADQ(7, 56,57,58,59,60,61,62,63)
  // stages s1..s6 (runs <= 64): pure in-register, unrolled (~11 KB)
  P_M1(CEP,0)
  P_M3(CEP,0) P_M1(CEP,0)
  P_M7(CEP,0) P_M2(CEP,0) P_M1(CEP,0)
  P_M15(CEP,0) P_M4(CEP,0) P_M2(CEP,0) P_M1(CEP,0)
  P_M31(CEP,0) P_M8(CEP,0) P_M4(CEP,0) P_M2(CEP,0) P_M1(CEP,0)
  P_M63(CEP,0) P_M16(CEP,0) P_M8(CEP,0) P_M4(CEP,0) P_M2(CEP,0) P_M1(CEP,0)
  // stages s7..s12: one generic merge-stage body looped 6x (I$-friendly)
  // fm = flip lane-mask (1,3,7,15,31,63); clean lane-masks (fm+1)>>2 .. 1
#pragma unroll 1
  for (int fm = 1; fm < 64; fm = 2 * fm + 1) {
    {
      const int pa_ = ((t ^ fm) & 63) << 2;
      const bool km_ = !(t & ((fm + 1) >> 1));
      P_M63(KFB, 0)
    }
#pragma unroll 1
    for (int jt = (fm + 1) >> 2; jt; jt >>= 1) {
      const int pa_ = ((t ^ jt) & 63) << 2;
      const bool km_ = !(t & jt);
      L64(KB, 0)
    }
    CLEAN6
  }
  // rank-weighted sum: rank of a{e} is 64t+e; lo half -> o0, hi half -> o1
  const float4* pw0 = (const float4*)(pwt + (size_t)o0 * 4096 + t * 64);
  const float4* pw1 = (const float4*)(pwt + (size_t)o1 * 4096 + t * 64);
  float s0 = 0.f, s1 = 0.f;
  POOLQ(0, 0,1,2,3)   POOLQ(1, 4,5,6,7)   POOLQ(2, 8,9,10,11)  POOLQ(3, 12,13,14,15)
  POOLQ(4, 16,17,18,19) POOLQ(5, 20,21,22,23) POOLQ(6, 24,25,26,27) POOLQ(7, 28,29,30,31)
  POOLQ(8, 32,33,34,35) POOLQ(9, 36,37,38,39) POOLQ(10, 40,41,42,43) POOLQ(11, 44,45,46,47)
  POOLQ(12, 48,49,50,51) POOLQ(13, 52,53,54,55) POOLQ(14, 56,57,58,59) POOLQ(15, 60,61,62,63)
#pragma unroll
  for (int off = 32; off > 0; off >>= 1) {
    s0 += __shfl_xor(s0, off);
    s1 += __shfl_xor(s1, off);
  }
  if (t == 0) {
    out[b * 256 + o0] = s0;
    out[b * 256 + o1] = s1;
  }
}

extern "C" void kernel_launch(void* const* d_in, const int* in_sizes, int n_in,
                              void* d_out, int out_size, void* d_ws, size_t ws_size,
                              hipStream_t stream) {
  const float* x  = (const float*)d_in[0];
  const float* w1 = (const float*)d_in[1];
  const float* b1 = (const float*)d_in[2];
  const float* w2 = (const float*)d_in[3];
  const float* b2 = (const float*)d_in[4];
  const float* pw = (const float*)d_in[5];
  char* ws = (char*)d_ws;
  _Float16* u   = (_Float16*)ws;                                   // 2 MiB
  _Float16* v   = (_Float16*)(ws + (2u << 20));                    // 2 MiB
  _Float16* w2t = (_Float16*)(ws + (4u << 20));                    // 256 KiB
  float*    pwt = (float*)(ws + (5u << 20));                       // 4 MiB
  unsigned short* yt = (unsigned short*)(ws + (9u << 20));         // 64 MiB f16
  float* out = (float*)d_out;

  k_prep<<<dim3(768), dim3(256), 0, stream>>>(x, w1, b1, w2, pw, u, v, w2t, pwt);
  k_gemm<<<dim3(512), dim3(256), 0, stream>>>(u, v, w2t, b2, yt);
  k_sortpool<<<dim3(4096), dim3(64), 0, stream>>>(yt, pwt, out);
}

// Round 18
// 148.936 us; speedup vs baseline: 1.1045x; 1.1045x over previous
//
#include <hip/hip_runtime.h>
#include <hip/hip_bf16.h>
#include <hip/hip_fp16.h>

typedef __attribute__((ext_vector_type(4))) float f32x4;
typedef _Float16 h8 __attribute__((ext_vector_type(8)));
typedef int i32x4 __attribute__((ext_vector_type(4)));
typedef _Float16 h2 __attribute__((ext_vector_type(2)));

static __device__ __forceinline__ h2 ih2(int x) { return __builtin_bit_cast(h2, x); }
static __device__ __forceinline__ unsigned pkrtz(float lo, float hi) {
  return __builtin_bit_cast(unsigned, __builtin_amdgcn_cvt_pkrtz(lo, hi));
}
// inline-asm packed f16 ops
static __device__ __forceinline__ int pkmin(int x, int y) {
  int d; asm("v_pk_min_f16 %0, %1, %2" : "=v"(d) : "v"(x), "v"(y)); return d;
}
static __device__ __forceinline__ int pkmax(int x, int y) {
  int d; asm("v_pk_max_f16 %0, %1, %2" : "=v"(d) : "v"(x), "v"(y)); return d;
}
static __device__ __forceinline__ int pkadd(int x, int y) {
  int d; asm("v_pk_add_f16 %0, %1, %2" : "=v"(d) : "v"(x), "v"(y)); return d;
}

// Problem constants: B=32, L=64, C=128, D=512, O=256, L2=4096

// ------ K1 (fused prep): u,v = f16(x@w1 split + b1); w2t; pwt ------------
__global__ __launch_bounds__(256) void k_prep(const float* __restrict__ x,
                                              const float* __restrict__ w1,
                                              const float* __restrict__ b1,
                                              const float* __restrict__ w2,
                                              const float* __restrict__ pw,
                                              _Float16* __restrict__ u,
                                              _Float16* __restrict__ v,
                                              _Float16* __restrict__ w2t,
                                              float* __restrict__ pwt) {
  __shared__ float xs[8 * 128];
  int bid = blockIdx.x;
  int t = threadIdx.x;
  if (bid < 256) {
    int r0 = bid * 8;
    ((float4*)xs)[t] = ((const float4*)(x + (size_t)r0 * 128))[t];
    __syncthreads();
    int d1 = t, d2 = t + 256;
    float au0[8], au1[8], av0[8], av1[8];
    float bb1 = b1[d1], bb2 = b1[d2];
#pragma unroll
    for (int r = 0; r < 8; ++r) { au0[r] = bb1; au1[r] = bb2; av0[r] = 0.f; av1[r] = 0.f; }
#pragma unroll 4
    for (int c = 0; c < 128; ++c) {
      float wu1 = w1[c * 512 + d1];
      float wu2 = w1[c * 512 + d2];
      float wv1 = w1[(c + 128) * 512 + d1];
      float wv2 = w1[(c + 128) * 512 + d2];
#pragma unroll
      for (int r = 0; r < 8; ++r) {
        float xv = xs[r * 128 + c];
        au0[r] = fmaf(xv, wu1, au0[r]);
        au1[r] = fmaf(xv, wu2, au1[r]);
        av0[r] = fmaf(xv, wv1, av0[r]);
        av1[r] = fmaf(xv, wv2, av1[r]);
      }
    }
#pragma unroll
    for (int r = 0; r < 8; ++r) {
      u[(size_t)(r0 + r) * 512 + d1] = (_Float16)au0[r];
      u[(size_t)(r0 + r) * 512 + d2] = (_Float16)au1[r];
      v[(size_t)(r0 + r) * 512 + d1] = (_Float16)av0[r];
      v[(size_t)(r0 + r) * 512 + d2] = (_Float16)av1[r];
    }
  } else if (bid < 512) {
    int n = bid - 256;
    w2t[(size_t)n * 512 + t]       = (_Float16)w2[(size_t)t * 256 + n];
    w2t[(size_t)n * 512 + t + 256] = (_Float16)w2[(size_t)(t + 256) * 256 + n];
  } else {
    int o = bid - 512;
#pragma unroll
    for (int it = 0; it < 16; ++it) {
      int l = it * 256 + t;
      pwt[(size_t)o * 4096 + l] = pw[(size_t)l * 256 + o];
    }
  }
}

// ---- K4: K-split staging (36 KiB LDS -> 4 blocks/CU) -------------------
__global__ __launch_bounds__(256, 2) void k_gemm(const _Float16* __restrict__ u,
                                                 const _Float16* __restrict__ v,
                                                 const _Float16* __restrict__ w2t,
                                                 const float* __restrict__ b2,
                                                 unsigned short* __restrict__ yt) {
  __shared__ char vl[64 * 512];   // 64 rows x 256 f16 (one K-half), swizzled
  __shared__ char ulm[4 * 1024];  // 4 u-rows x 512 f16 (full K)
  int t = threadIdx.x;
  int n0 = blockIdx.x;                     // 512 blocks
  int bid = (n0 & 7) * 64 + (n0 >> 3);     // XCD-bijective: same-b same XCD
  int b = bid >> 4, ig = bid & 15;
  {
    const char* usrc = (const char*)(u + (size_t)(b * 64 + ig * 4) * 512);
    *(uint4*)(ulm + t * 16) = *(const uint4*)(usrc + t * 16);
  }
  int w = t >> 6, l = t & 63, lr = l & 15, lg = l >> 4;
  const _Float16* bptr[4];
  float bias[4];
#pragma unroll
  for (int ni = 0; ni < 4; ++ni) {
    int col = w * 64 + ni * 16 + lr;
    bptr[ni] = w2t + (size_t)col * 512 + lg * 8;
    bias[ni] = b2[col];
  }
#pragma unroll 1
  for (int ih = 0; ih < 2; ++ih) {  // i-pairs: i = ig*4 + ih*2 + {0,1}
    f32x4 acc[2][4][4];
#pragma unroll
    for (int ip = 0; ip < 2; ++ip)
#pragma unroll
      for (int mi = 0; mi < 4; ++mi)
#pragma unroll
        for (int ni = 0; ni < 4; ++ni) {
          float bv = bias[ni];
          f32x4 ci = {bv, bv, bv, bv};
          acc[ip][mi][ni] = ci;
        }
#pragma unroll 1
    for (int half = 0; half < 2; ++half) {
      __syncthreads();  // vl reusable (also covers ulm on first pass)
      {
        const char* vsrc = (const char*)(v + (size_t)b * 64 * 512 + half * 256);
#pragma unroll
        for (int it = 0; it < 8; ++it) {
          int f = it * 4096 + t * 16;   // 0..32767 within the half-tile
          int row = f >> 9;             // 512-byte rows
          int cb = f & 511;
          uint4 d = *(const uint4*)(vsrc + (size_t)row * 1024 + cb);
          *(uint4*)(vl + (f ^ ((row & 7) << 4))) = d;
        }
      }
      __syncthreads();
#pragma unroll 2
      for (int kq = 0; kq < 8; ++kq) {
        int kk = half * 8 + kq;
        h8 bfv[4];
#pragma unroll
        for (int ni = 0; ni < 4; ++ni) bfv[ni] = *(const h8*)(bptr[ni] + kk * 32);
        i32x4 vf[4];
#pragma unroll
        for (int mi = 0; mi < 4; ++mi) {
          int row = mi * 16 + lr;
          int fb = row * 512 + kq * 64 + lg * 16;
          vf[mi] = *(const i32x4*)(vl + (fb ^ ((row & 7) << 4)));
        }
#pragma unroll
        for (int ip = 0; ip < 2; ++ip) {
          i32x4 uf = *(const i32x4*)(ulm + (ih * 2 + ip) * 1024 + kk * 64 + lg * 16);
#pragma unroll
          for (int mi = 0; mi < 4; ++mi) {
            i32x4 aw;
#pragma unroll
            for (int q = 0; q < 4; ++q) aw[q] = pkmax(pkadd(uf[q], vf[mi][q]), 0);
            h8 af = __builtin_bit_cast(h8, aw);
#pragma unroll
            for (int ni = 0; ni < 4; ++ni)
              acc[ip][mi][ni] =
                  __builtin_amdgcn_mfma_f32_16x16x32_f16(af, bfv[ni], acc[ip][mi][ni], 0, 0, 0);
          }
        }
      }
    }
#pragma unroll
    for (int ip = 0; ip < 2; ++ip) {
      int i = ig * 4 + ih * 2 + ip;
#pragma unroll
      for (int ni = 0; ni < 4; ++ni) {
        int col = w * 64 + ni * 16 + lr;
        unsigned short* colbase = yt + (size_t)(b * 256 + col) * 4096 + (size_t)i * 64;
#pragma unroll
        for (int mi = 0; mi < 4; ++mi) {
          f32x4 vv = acc[ip][mi][ni];
          uint2 st;
          st.x = pkrtz(vv[0], vv[1]);
          st.y = pkrtz(vv[2], vv[3]);
          *(uint2*)(colbase + mi * 16 + lg * 4) = st;
        }
      }
    }
  }
}

// -- K5: E=64 single-wave sort, scalarized (round-16, measured 84 us) ----
#define DPP_X1 0xB1
#define DPP_X2 0x4E
#define DPP_X3 0x1B
#define DPP_X7 0x141
#define DPP_X8 0x128
#define DPP_XF 0x140

#define CEP(x, y, C) { int lo_ = pkmin(a##x, a##y); int hi_ = pkmax(a##x, a##y); a##x = lo_; a##y = hi_; }
#define KC(e, CTRL) { int r_ = __builtin_amdgcn_mov_dpp(a##e, CTRL, 0xf, 0xf, true); int mn_ = pkmin(a##e, r_); int mx_ = pkmax(a##e, r_); a##e = km_ ? mn_ : mx_; }
#define KB(e, C) { int r_ = __builtin_amdgcn_ds_bpermute(pa_, a##e); int mn_ = pkmin(a##e, r_); int mx_ = pkmax(a##e, r_); a##e = km_ ? mn_ : mx_; }
#define KFD(x, y, CTRL) { int r0_ = __builtin_amdgcn_mov_dpp(a##y, CTRL, 0xf, 0xf, true); int r1_ = __builtin_amdgcn_mov_dpp(a##x, CTRL, 0xf, 0xf, true); int mn0_ = pkmin(a##x, r0_); int mx0_ = pkmax(a##x, r0_); int mn1_ = pkmin(a##y, r1_); int mx1_ = pkmax(a##y, r1_); a##x = km_ ? mn0_ : mx0_; a##y = km_ ? mn1_ : mx1_; }
#define KFB(x, y, C) { int r0_ = __builtin_amdgcn_ds_bpermute(pa_, a##y); int r1_ = __builtin_amdgcn_ds_bpermute(pa_, a##x); int mn0_ = pkmin(a##x, r0_); int mx0_ = pkmax(a##x, r0_); int mn1_ = pkmin(a##y, r1_); int mx1_ = pkmax(a##y, r1_); a##x = km_ ? mn0_ : mx0_; a##y = km_ ? mn1_ : mx1_; }

#define L64(F,C) F(0,C)F(1,C)F(2,C)F(3,C)F(4,C)F(5,C)F(6,C)F(7,C)F(8,C)F(9,C)F(10,C)F(11,C)F(12,C)F(13,C)F(14,C)F(15,C)F(16,C)F(17,C)F(18,C)F(19,C)F(20,C)F(21,C)F(22,C)F(23,C)F(24,C)F(25,C)F(26,C)F(27,C)F(28,C)F(29,C)F(30,C)F(31,C)F(32,C)F(33,C)F(34,C)F(35,C)F(36,C)F(37,C)F(38,C)F(39,C)F(40,C)F(41,C)F(42,C)F(43,C)F(44,C)F(45,C)F(46,C)F(47,C)F(48,C)F(49,C)F(50,C)F(51,C)F(52,C)F(53,C)F(54,C)F(55,C)F(56,C)F(57,C)F(58,C)F(59,C)F(60,C)F(61,C)F(62,C)F(63,C)
#define P_M1(F,C) F(0,1,C)F(2,3,C)F(4,5,C)F(6,7,C)F(8,9,C)F(10,11,C)F(12,13,C)F(14,15,C)F(16,17,C)F(18,19,C)F(20,21,C)F(22,23,C)F(24,25,C)F(26,27,C)F(28,29,C)F(30,31,C)F(32,33,C)F(34,35,C)F(36,37,C)F(38,39,C)F(40,41,C)F(42,43,C)F(44,45,C)F(46,47,C)F(48,49,C)F(50,51,C)F(52,53,C)F(54,55,C)F(56,57,C)F(58,59,C)F(60,61,C)F(62,63,C)
#define P_M2(F,C) F(0,2,C)F(1,3,C)F(4,6,C)F(5,7,C)F(8,10,C)F(9,11,C)F(12,14,C)F(13,15,C)F(16,18,C)F(17,19,C)F(20,22,C)F(21,23,C)F(24,26,C)F(25,27,C)F(28,30,C)F(29,31,C)F(32,34,C)F(33,35,C)F(36,38,C)F(37,39,C)F(40,42,C)F(41,43,C)F(44,46,C)F(45,47,C)F(48,50,C)F(49,51,C)F(52,54,C)F(53,55,C)F(56,58,C)F(57,59,C)F(60,62,C)F(61,63,C)
#define P_M3(F,C) F(0,3,C)F(1,2,C)F(4,7,C)F(5,6,C)F(8,11,C)F(9,10,C)F(12,15,C)F(13,14,C)F(16,19,C)F(17,18,C)F(20,23,C)F(21,22,C)F(24,27,C)F(25,26,C)F(28,31,C)F(29,30,C)F(32,35,C)F(33,34,C)F(36,39,C)F(37,38,C)F(40,43,C)F(41,42,C)F(44,47,C)F(45,46,C)F(48,51,C)F(49,50,C)F(52,55,C)F(53,54,C)F(56,59,C)F(57,58,C)F(60,63,C)F(61,62,C)
#define P_M4(F,C) F(0,4,C)F(1,5,C)F(2,6,C)F(3,7,C)F(8,12,C)F(9,13,C)F(10,14,C)F(11,15,C)F(16,20,C)F(17,21,C)F(18,22,C)F(19,23,C)F(24,28,C)F(25,29,C)F(26,30,C)F(27,31,C)F(32,36,C)F(33,37,C)F(34,38,C)F(35,39,C)F(40,44,C)F(41,45,C)F(42,46,C)F(43,47,C)F(48,52,C)F(49,53,C)F(50,54,C)F(51,55,C)F(56,60,C)F(57,61,C)F(58,62,C)F(59,63,C)
#define P_M7(F,C) F(0,7,C)F(1,6,C)F(2,5,C)F(3,4,C)F(8,15,C)F(9,14,C)F(10,13,C)F(11,12,C)F(16,23,C)F(17,22,C)F(18,21,C)F(19,20,C)F(24,31,C)F(25,30,C)F(26,29,C)F(27,28,C)F(32,39,C)F(33,38,C)F(34,37,C)F(35,36,C)F(40,47,C)F(41,46,C)F(42,45,C)F(43,44,C)F(48,55,C)F(49,54,C)F(50,53,C)F(51,52,C)F(56,63,C)F(57,62,C)F(58,61,C)F(59,60,C)
#define P_M8(F,C) F(0,8,C)F(1,9,C)F(2,10,C)F(3,11,C)F(4,12,C)F(5,13,C)F(6,14,C)F(7,15,C)F(16,24,C)F(17,25,C)F(18,26,C)F(19,27,C)F(20,28,C)F(21,29,C)F(22,30,C)F(23,31,C)F(32,40,C)F(33,41,C)F(34,42,C)F(35,43,C)F(36,44,C)F(37,45,C)F(38,46,C)F(39,47,C)F(48,56,C)F(49,57,C)F(50,58,C)F(51,59,C)F(52,60,C)F(53,61,C)F(54,62,C)F(55,63,C)
#define P_M15(F,C) F(0,15,C)F(1,14,C)F(2,13,C)F(3,12,C)F(4,11,C)F(5,10,C)F(6,9,C)F(7,8,C)F(16,31,C)F(17,30,C)F(18,29,C)F(19,28,C)F(20,27,C)F(21,26,C)F(22,25,C)F(23,24,C)F(32,47,C)F(33,46,C)F(34,45,C)F(35,44,C)F(36,43,C)F(37,42,C)F(38,41,C)F(39,40,C)F(48,63,C)F(49,62,C)F(50,61,C)F(51,60,C)F(52,59,C)F(53,58,C)F(54,57,C)F(55,56,C)
#define P_M16(F,C) F(0,16,C)F(1,17,C)F(2,18,C)F(3,19,C)F(4,20,C)F(5,21,C)F(6,22,C)F(7,23,C)F(8,24,C)F(9,25,C)F(10,26,C)F(11,27,C)F(12,28,C)F(13,29,C)F(14,30,C)F(15,31,C)F(32,48,C)F(33,49,C)F(34,50,C)F(35,51,C)F(36,52,C)F(37,53,C)F(38,54,C)F(39,55,C)F(40,56,C)F(41,57,C)F(42,58,C)F(43,59,C)F(44,60,C)F(45,61,C)F(46,62,C)F(47,63,C)
#define P_M31(F,C) F(0,31,C)F(1,30,C)F(2,29,C)F(3,28,C)F(4,27,C)F(5,26,C)F(6,25,C)F(7,24,C)F(8,23,C)F(9,22,C)F(10,21,C)F(11,20,C)F(12,19,C)F(13,18,C)F(14,17,C)F(15,16,C)F(32,63,C)F(33,62,C)F(34,61,C)F(35,60,C)F(36,59,C)F(37,58,C)F(38,57,C)F(39,56,C)F(40,55,C)F(41,54,C)F(42,53,C)F(43,52,C)F(44,51,C)F(45,50,C)F(46,49,C)F(47,48,C)
#define P_M32(F,C) F(0,32,C)F(1,33,C)F(2,34,C)F(3,35,C)F(4,36,C)F(5,37,C)F(6,38,C)F(7,39,C)F(8,40,C)F(9,41,C)F(10,42,C)F(11,43,C)F(12,44,C)F(13,45,C)F(14,46,C)F(15,47,C)F(16,48,C)F(17,49,C)F(18,50,C)F(19,51,C)F(20,52,C)F(21,53,C)F(22,54,C)F(23,55,C)F(24,56,C)F(25,57,C)F(26,58,C)F(27,59,C)F(28,60,C)F(29,61,C)F(30,62,C)F(31,63,C)
#define P_M63(F,C) F(0,63,C)F(1,62,C)F(2,61,C)F(3,60,C)F(4,59,C)F(5,58,C)F(6,57,C)F(7,56,C)F(8,55,C)F(9,54,C)F(10,53,C)F(11,52,C)F(12,51,C)F(13,50,C)F(14,49,C)F(15,48,C)F(16,47,C)F(17,46,C)F(18,45,C)F(19,44,C)F(20,43,C)F(21,42,C)F(22,41,C)F(23,40,C)F(24,39,C)F(25,38,C)F(26,37,C)F(27,36,C)F(28,35,C)F(29,34,C)F(30,33,C)F(31,32,C)

#define CLEAN6 P_M32(CEP,0) P_M16(CEP,0) P_M8(CEP,0) P_M4(CEP,0) P_M2(CEP,0) P_M1(CEP,0)

#define LOADQ(q,E0,E1,E2,E3,E4,E5,E6,E7) { uint4 x0_ = c0[q], x1_ = c1[q]; \
  a##E0 = (int)((x0_.x & 0xffffu) | (x1_.x << 16)); a##E1 = (int)((x0_.x >> 16) | (x1_.x & 0xffff0000u)); \
  a##E2 = (int)((x0_.y & 0xffffu) | (x1_.y << 16)); a##E3 = (int)((x0_.y >> 16) | (x1_.y & 0xffff0000u)); \
  a##E4 = (int)((x0_.z & 0xffffu) | (x1_.z << 16)); a##E5 = (int)((x0_.z >> 16) | (x1_.z & 0xffff0000u)); \
  a##E6 = (int)((x0_.w & 0xffffu) | (x1_.w << 16)); a##E7 = (int)((x0_.w >> 16) | (x1_.w & 0xffff0000u)); }

#define POOLQ(q,E0,E1,E2,E3) { float4 w0_ = pw0[q], w1_ = pw1[q]; h2 v_; \
  v_ = ih2(a##E0); s0 = fmaf((float)v_[0], w0_.x, s0); s1 = fmaf((float)v_[1], w1_.x, s1); \
  v_ = ih2(a##E1); s0 = fmaf((float)v_[0], w0_.y, s0); s1 = fmaf((float)v_[1], w1_.y, s1); \
  v_ = ih2(a##E2); s0 = fmaf((float)v_[0], w0_.z, s0); s1 = fmaf((float)v_[1], w1_.z, s1); \
  v_ = ih2(a##E3); s0 = fmaf((float)v_[0], w0_.w, s0); s1 = fmaf((float)v_[1], w1_.w, s1); }

__global__ __launch_bounds__(64, 2) void k_sortpool(const unsigned short* __restrict__ yt,
                                                    const float* __restrict__ pwt,
                                                    float* __restrict__ out) {
  int t = threadIdx.x;  // lane 0..63 (one wave per block)
  int b = blockIdx.x >> 7, p = blockIdx.x & 127;
  int o0 = p * 2, o1 = o0 + 1;
  const uint4* c0 = (const uint4*)(yt + (size_t)(b * 256 + o0) * 4096 + t * 64);
  const uint4* c1 = (const uint4*)(yt + (size_t)(b * 256 + o1) * 4096 + t * 64);
  int a0,a1,a2,a3,a4,a5,a6,a7,a8,a9,a10,a11,a12,a13,a14,a15,
      a16,a17,a18,a19,a20,a21,a22,a23,a24,a25,a26,a27,a28,a29,a30,a31,
      a32,a33,a34,a35,a36,a37,a38,a39,a40,a41,a42,a43,a44,a45,a46,a47,
      a48,a49,a50,a51,a52,a53,a54,a55,a56,a57,a58,a59,a60,a61,a62,a63;
  LOADQ(0, 0,1,2,3,4,5,6,7)
  LOADQ(1, 8,9,10,11,12,13,14,15)
  LOADQ(2, 16,17,18,19,20,21,22,23)
  LOADQ(3, 24,25,26,27,28,29,30,31)
  LOADQ(4, 32,33,34,35,36,37,38,39)
  LOADQ(5, 40,41,42,43,44,45,46,47)
  LOADQ(6, 48,49,50,51,52,53,54,55)
  LOADQ(7, 56,57,58,59,60,61,62,63)
  // stages s1..s6 (runs <= 64): pure in-register
  P_M1(CEP,0)
  P_M3(CEP,0) P_M1(CEP,0)
  P_M7(CEP,0) P_M2(CEP,0) P_M1(CEP,0)
  P_M15(CEP,0) P_M4(CEP,0) P_M2(CEP,0) P_M1(CEP,0)
  P_M31(CEP,0) P_M8(CEP,0) P_M4(CEP,0) P_M2(CEP,0) P_M1(CEP,0)
  P_M63(CEP,0) P_M16(CEP,0) P_M8(CEP,0) P_M4(CEP,0) P_M2(CEP,0) P_M1(CEP,0)
  // s7 -> 128-runs
  { const bool km_ = !(t & 1); P_M63(KFD, DPP_X1) } CLEAN6
  // s8 -> 256
  { const bool km_ = !(t & 2); P_M63(KFD, DPP_X3) }
  { const bool km_ = !(t & 1); L64(KC, DPP_X1) } CLEAN6
  // s9 -> 512
  { const bool km_ = !(t & 4); P_M63(KFD, DPP_X7) }
  { const bool km_ = !(t & 2); L64(KC, DPP_X2) }
  { const bool km_ = !(t & 1); L64(KC, DPP_X1) } CLEAN6
  // s10 -> 1024
  { const bool km_ = !(t & 8); P_M63(KFD, DPP_XF) }
  { const bool km_ = !(t & 4); const int pa_ = ((t ^ 4) & 63) << 2; L64(KB, 0) }
  { const bool km_ = !(t & 2); L64(KC, DPP_X2) }
  { const bool km_ = !(t & 1); L64(KC, DPP_X1) } CLEAN6
  // s11 -> 2048
  { const bool km_ = !(t & 16); const int pa_ = ((t ^ 31) & 63) << 2; P_M63(KFB, 0) }
  { const bool km_ = !(t & 8); L64(KC, DPP_X8) }
  { const bool km_ = !(t & 4); const int pa_ = ((t ^ 4) & 63) << 2; L64(KB, 0) }
  { const bool km_ = !(t & 2); L64(KC, DPP_X2) }
  { const bool km_ = !(t & 1); L64(KC, DPP_X1) } CLEAN6
  // s12 -> 4096
  { const bool km_ = !(t & 32); const int pa_ = ((t ^ 63) & 63) << 2; P_M63(KFB, 0) }
  { const bool km_ = !(t & 16); const int pa_ = ((t ^ 16) & 63) << 2; L64(KB, 0) }
  { const bool km_ = !(t & 8); L64(KC, DPP_X8) }
  { const bool km_ = !(t & 4); const int pa_ = ((t ^ 4) & 63) << 2; L64(KB, 0) }
  { const bool km_ = !(t & 2); L64(KC, DPP_X2) }
  { const bool km_ = !(t & 1); L64(KC, DPP_X1) } CLEAN6
  // rank-weighted sum: rank of a{e} is 64t+e; lo half -> o0, hi half -> o1
  const float4* pw0 = (const float4*)(pwt + (size_t)o0 * 4096 + t * 64);
  const float4* pw1 = (const float4*)(pwt + (size_t)o1 * 4096 + t * 64);
  float s0 = 0.f, s1 = 0.f;
  POOLQ(0, 0,1,2,3)   POOLQ(1, 4,5,6,7)   POOLQ(2, 8,9,10,11)  POOLQ(3, 12,13,14,15)
  POOLQ(4, 16,17,18,19) POOLQ(5, 20,21,22,23) POOLQ(6, 24,25,26,27) POOLQ(7, 28,29,30,31)
  POOLQ(8, 32,33,34,35) POOLQ(9, 36,37,38,39) POOLQ(10, 40,41,42,43) POOLQ(11, 44,45,46,47)
  POOLQ(12, 48,49,50,51) POOLQ(13, 52,53,54,55) POOLQ(14, 56,57,58,59) POOLQ(15, 60,61,62,63)
#pragma unroll
  for (int off = 32; off > 0; off >>= 1) {
    s0 += __shfl_xor(s0, off);
    s1 += __shfl_xor(s1, off);
  }
  if (t == 0) {
    out[b * 256 + o0] = s0;
    out[b * 256 + o1] = s1;
  }
}

extern "C" void kernel_launch(void* const* d_in, const int* in_sizes, int n_in,
                              void* d_out, int out_size, void* d_ws, size_t ws_size,
                              hipStream_t stream) {
  const float* x  = (const float*)d_in[0];
  const float* w1 = (const float*)d_in[1];
  const float* b1 = (const float*)d_in[2];
  const float* w2 = (const float*)d_in[3];
  const float* b2 = (const float*)d_in[4];
  const float* pw = (const float*)d_in[5];
  char* ws = (char*)d_ws;
  _Float16* u   = (_Float16*)ws;                                   // 2 MiB
  _Float16* v   = (_Float16*)(ws + (2u << 20));                    // 2 MiB
  _Float16* w2t = (_Float16*)(ws + (4u << 20));                    // 256 KiB
  float*    pwt = (float*)(ws + (5u << 20));                       // 4 MiB
  unsigned short* yt = (unsigned short*)(ws + (9u << 20));         // 64 MiB f16
  float* out = (float*)d_out;

  k_prep<<<dim3(768), dim3(256), 0, stream>>>(x, w1, b1, w2, pw, u, v, w2t, pwt);
  k_gemm<<<dim3(512), dim3(256), 0, stream>>>(u, v, w2t, b2, yt);
  k_sortpool<<<dim3(4096), dim3(64), 0, stream>>>(yt, pwt, out);
}

// Round 19
// 145.907 us; speedup vs baseline: 1.1274x; 1.0208x over previous
//
#include <hip/hip_runtime.h>
#include <hip/hip_bf16.h>
#include <hip/hip_fp16.h>

typedef __attribute__((ext_vector_type(4))) float f32x4;
typedef _Float16 h8 __attribute__((ext_vector_type(8)));
typedef int i32x4 __attribute__((ext_vector_type(4)));
typedef _Float16 h2 __attribute__((ext_vector_type(2)));

static __device__ __forceinline__ h2 ih2(int x) { return __builtin_bit_cast(h2, x); }
static __device__ __forceinline__ unsigned pkrtz(float lo, float hi) {
  return __builtin_bit_cast(unsigned, __builtin_amdgcn_cvt_pkrtz(lo, hi));
}
// inline-asm packed f16 ops
static __device__ __forceinline__ int pkmin(int x, int y) {
  int d; asm("v_pk_min_f16 %0, %1, %2" : "=v"(d) : "v"(x), "v"(y)); return d;
}
static __device__ __forceinline__ int pkmax(int x, int y) {
  int d; asm("v_pk_max_f16 %0, %1, %2" : "=v"(d) : "v"(x), "v"(y)); return d;
}
static __device__ __forceinline__ int pkadd(int x, int y) {
  int d; asm("v_pk_add_f16 %0, %1, %2" : "=v"(d) : "v"(x), "v"(y)); return d;
}

// Problem constants: B=32, L=64, C=128, D=512, O=256, L2=4096

// ------ K1 (fused prep): u,v = f16(x@w1 split + b1); w2t; pwt ------------
__global__ __launch_bounds__(256) void k_prep(const float* __restrict__ x,
                                              const float* __restrict__ w1,
                                              const float* __restrict__ b1,
                                              const float* __restrict__ w2,
                                              const float* __restrict__ pw,
                                              _Float16* __restrict__ u,
                                              _Float16* __restrict__ v,
                                              _Float16* __restrict__ w2t,
                                              float* __restrict__ pwt) {
  __shared__ float xs[8 * 128];
  int bid = blockIdx.x;
  int t = threadIdx.x;
  if (bid < 256) {
    int r0 = bid * 8;
    ((float4*)xs)[t] = ((const float4*)(x + (size_t)r0 * 128))[t];
    __syncthreads();
    int d1 = t, d2 = t + 256;
    float au0[8], au1[8], av0[8], av1[8];
    float bb1 = b1[d1], bb2 = b1[d2];
#pragma unroll
    for (int r = 0; r < 8; ++r) { au0[r] = bb1; au1[r] = bb2; av0[r] = 0.f; av1[r] = 0.f; }
#pragma unroll 4
    for (int c = 0; c < 128; ++c) {
      float wu1 = w1[c * 512 + d1];
      float wu2 = w1[c * 512 + d2];
      float wv1 = w1[(c + 128) * 512 + d1];
      float wv2 = w1[(c + 128) * 512 + d2];
#pragma unroll
      for (int r = 0; r < 8; ++r) {
        float xv = xs[r * 128 + c];
        au0[r] = fmaf(xv, wu1, au0[r]);
        au1[r] = fmaf(xv, wu2, au1[r]);
        av0[r] = fmaf(xv, wv1, av0[r]);
        av1[r] = fmaf(xv, wv2, av1[r]);
      }
    }
#pragma unroll
    for (int r = 0; r < 8; ++r) {
      u[(size_t)(r0 + r) * 512 + d1] = (_Float16)au0[r];
      u[(size_t)(r0 + r) * 512 + d2] = (_Float16)au1[r];
      v[(size_t)(r0 + r) * 512 + d1] = (_Float16)av0[r];
      v[(size_t)(r0 + r) * 512 + d2] = (_Float16)av1[r];
    }
  } else if (bid < 512) {
    int n = bid - 256;
    w2t[(size_t)n * 512 + t]       = (_Float16)w2[(size_t)t * 256 + n];
    w2t[(size_t)n * 512 + t + 256] = (_Float16)w2[(size_t)(t + 256) * 256 + n];
  } else {
    int o = bid - 512;
#pragma unroll
    for (int it = 0; it < 16; ++it) {
      int l = it * 256 + t;
      pwt[(size_t)o * 4096 + l] = pw[(size_t)l * 256 + o];
    }
  }
}

// ---- K4: register-built h = relu(u_i + v_j) -> f16 MFMA -> f16 y^T -----
// 512 blocks: (b, ig of 4 i-rows); v-tile 64x512 f16 staged once, 1 barrier
__global__ __launch_bounds__(256, 2) void k_gemm(const _Float16* __restrict__ u,
                                                 const _Float16* __restrict__ v,
                                                 const _Float16* __restrict__ w2t,
                                                 const float* __restrict__ b2,
                                                 unsigned short* __restrict__ yt) {
  __shared__ char vl[64 * 1024];  // 64 rows x 512 f16, XOR-swizzled
  __shared__ char ulm[4 * 1024];  // 4 u-rows x 512 f16
  int t = threadIdx.x;
  int n0 = blockIdx.x;                     // 512 blocks
  int bid = (n0 & 7) * 64 + (n0 >> 3);     // XCD-bijective: same-b same XCD
  int b = bid >> 4, ig = bid & 15;
  {
    const char* vsrc = (const char*)(v + (size_t)b * 64 * 512);
#pragma unroll
    for (int it = 0; it < 16; ++it) {
      int f = it * 4096 + t * 16;
      uint4 d = *(const uint4*)(vsrc + f);
      int row = f >> 10;
      *(uint4*)(vl + (f ^ ((row & 7) << 4))) = d;
    }
    const char* usrc = (const char*)(u + (size_t)(b * 64 + ig * 4) * 512);
    int f = t * 16;
    *(uint4*)(ulm + f) = *(const uint4*)(usrc + f);
  }
  __syncthreads();
  int w = t >> 6, l = t & 63, lr = l & 15, lg = l >> 4;
  const _Float16* bptr[4];
  float bias[4];
#pragma unroll
  for (int ni = 0; ni < 4; ++ni) {
    int col = w * 64 + ni * 16 + lr;
    bptr[ni] = w2t + (size_t)col * 512 + lg * 8;
    bias[ni] = b2[col];
  }
#pragma unroll 1
  for (int ih = 0; ih < 2; ++ih) {  // i-pairs: i = ig*4 + ih*2 + {0,1}
    f32x4 acc[2][4][4];
#pragma unroll
    for (int ip = 0; ip < 2; ++ip)
#pragma unroll
      for (int mi = 0; mi < 4; ++mi)
#pragma unroll
        for (int ni = 0; ni < 4; ++ni) {
          float bv = bias[ni];
          f32x4 ci = {bv, bv, bv, bv};
          acc[ip][mi][ni] = ci;
        }
#pragma unroll 2
    for (int kk = 0; kk < 16; ++kk) {
      h8 bfv[4];
#pragma unroll
      for (int ni = 0; ni < 4; ++ni) bfv[ni] = *(const h8*)(bptr[ni] + kk * 32);
      i32x4 vf[4];
#pragma unroll
      for (int mi = 0; mi < 4; ++mi) {
        int row = mi * 16 + lr;
        int fb = row * 1024 + kk * 64 + lg * 16;
        vf[mi] = *(const i32x4*)(vl + (fb ^ ((row & 7) << 4)));
      }
#pragma unroll
      for (int ip = 0; ip < 2; ++ip) {
        i32x4 uf = *(const i32x4*)(ulm + (ih * 2 + ip) * 1024 + kk * 64 + lg * 16);
#pragma unroll
        for (int mi = 0; mi < 4; ++mi) {
          i32x4 aw;
#pragma unroll
          for (int q = 0; q < 4; ++q) aw[q] = pkmax(pkadd(uf[q], vf[mi][q]), 0);
          h8 af = __builtin_bit_cast(h8, aw);
#pragma unroll
          for (int ni = 0; ni < 4; ++ni)
            acc[ip][mi][ni] =
                __builtin_amdgcn_mfma_f32_16x16x32_f16(af, bfv[ni], acc[ip][mi][ni], 0, 0, 0);
        }
      }
    }
#pragma unroll
    for (int ip = 0; ip < 2; ++ip) {
      int i = ig * 4 + ih * 2 + ip;
#pragma unroll
      for (int ni = 0; ni < 4; ++ni) {
        int col = w * 64 + ni * 16 + lr;
        unsigned short* colbase = yt + (size_t)(b * 256 + col) * 4096 + (size_t)i * 64;
#pragma unroll
        for (int mi = 0; mi < 4; ++mi) {
          f32x4 vv = acc[ip][mi][ni];
          uint2 st;
          st.x = pkrtz(vv[0], vv[1]);
          st.y = pkrtz(vv[2], vv[3]);
          *(uint2*)(colbase + mi * 16 + lg * 4) = st;
        }
      }
    }
  }
}

// -- K5: E=64 single-wave sort, scalarized (measured 83.5 us) ------------
#define DPP_X1 0xB1
#define DPP_X2 0x4E
#define DPP_X3 0x1B
#define DPP_X7 0x141
#define DPP_X8 0x128
#define DPP_XF 0x140

#define CEP(x, y, C) { int lo_ = pkmin(a##x, a##y); int hi_ = pkmax(a##x, a##y); a##x = lo_; a##y = hi_; }
#define KC(e, CTRL) { int r_ = __builtin_amdgcn_mov_dpp(a##e, CTRL, 0xf, 0xf, true); int mn_ = pkmin(a##e, r_); int mx_ = pkmax(a##e, r_); a##e = km_ ? mn_ : mx_; }
#define KB(e, C) { int r_ = __builtin_amdgcn_ds_bpermute(pa_, a##e); int mn_ = pkmin(a##e, r_); int mx_ = pkmax(a##e, r_); a##e = km_ ? mn_ : mx_; }
#define KFD(x, y, CTRL) { int r0_ = __builtin_amdgcn_mov_dpp(a##y, CTRL, 0xf, 0xf, true); int r1_ = __builtin_amdgcn_mov_dpp(a##x, CTRL, 0xf, 0xf, true); int mn0_ = pkmin(a##x, r0_); int mx0_ = pkmax(a##x, r0_); int mn1_ = pkmin(a##y, r1_); int mx1_ = pkmax(a##y, r1_); a##x = km_ ? mn0_ : mx0_; a##y = km_ ? mn1_ : mx1_; }
#define KFB(x, y, C) { int r0_ = __builtin_amdgcn_ds_bpermute(pa_, a##y); int r1_ = __builtin_amdgcn_ds_bpermute(pa_, a##x); int mn0_ = pkmin(a##x, r0_); int mx0_ = pkmax(a##x, r0_); int mn1_ = pkmin(a##y, r1_); int mx1_ = pkmax(a##y, r1_); a##x = km_ ? mn0_ : mx0_; a##y = km_ ? mn1_ : mx1_; }

#define L64(F,C) F(0,C)F(1,C)F(2,C)F(3,C)F(4,C)F(5,C)F(6,C)F(7,C)F(8,C)F(9,C)F(10,C)F(11,C)F(12,C)F(13,C)F(14,C)F(15,C)F(16,C)F(17,C)F(18,C)F(19,C)F(20,C)F(21,C)F(22,C)F(23,C)F(24,C)F(25,C)F(26,C)F(27,C)F(28,C)F(29,C)F(30,C)F(31,C)F(32,C)F(33,C)F(34,C)F(35,C)F(36,C)F(37,C)F(38,C)F(39,C)F(40,C)F(41,C)F(42,C)F(43,C)F(44,C)F(45,C)F(46,C)F(47,C)F(48,C)F(49,C)F(50,C)F(51,C)F(52,C)F(53,C)F(54,C)F(55,C)F(56,C)F(57,C)F(58,C)F(59,C)F(60,C)F(61,C)F(62,C)F(63,C)
#define P_M1(F,C) F(0,1,C)F(2,3,C)F(4,5,C)F(6,7,C)F(8,9,C)F(10,11,C)F(12,13,C)F(14,15,C)F(16,17,C)F(18,19,C)F(20,21,C)F(22,23,C)F(24,25,C)F(26,27,C)F(28,29,C)F(30,31,C)F(32,33,C)F(34,35,C)F(36,37,C)F(38,39,C)F(40,41,C)F(42,43,C)F(44,45,C)F(46,47,C)F(48,49,C)F(50,51,C)F(52,53,C)F(54,55,C)F(56,57,C)F(58,59,C)F(60,61,C)F(62,63,C)
#define P_M2(F,C) F(0,2,C)F(1,3,C)F(4,6,C)F(5,7,C)F(8,10,C)F(9,11,C)F(12,14,C)F(13,15,C)F(16,18,C)F(17,19,C)F(20,22,C)F(21,23,C)F(24,26,C)F(25,27,C)F(28,30,C)F(29,31,C)F(32,34,C)F(33,35,C)F(36,38,C)F(37,39,C)F(40,42,C)F(41,43,C)F(44,46,C)F(45,47,C)F(48,50,C)F(49,51,C)F(52,54,C)F(53,55,C)F(56,58,C)F(57,59,C)F(60,62,C)F(61,63,C)
#define P_M3(F,C) F(0,3,C)F(1,2,C)F(4,7,C)F(5,6,C)F(8,11,C)F(9,10,C)F(12,15,C)F(13,14,C)F(16,19,C)F(17,18,C)F(20,23,C)F(21,22,C)F(24,27,C)F(25,26,C)F(28,31,C)F(29,30,C)F(32,35,C)F(33,34,C)F(36,39,C)F(37,38,C)F(40,43,C)F(41,42,C)F(44,47,C)F(45,46,C)F(48,51,C)F(49,50,C)F(52,55,C)F(53,54,C)F(56,59,C)F(57,58,C)F(60,63,C)F(61,62,C)
#define P_M4(F,C) F(0,4,C)F(1,5,C)F(2,6,C)F(3,7,C)F(8,12,C)F(9,13,C)F(10,14,C)F(11,15,C)F(16,20,C)F(17,21,C)F(18,22,C)F(19,23,C)F(24,28,C)F(25,29,C)F(26,30,C)F(27,31,C)F(32,36,C)F(33,37,C)F(34,38,C)F(35,39,C)F(40,44,C)F(41,45,C)F(42,46,C)F(43,47,C)F(48,52,C)F(49,53,C)F(50,54,C)F(51,55,C)F(56,60,C)F(57,61,C)F(58,62,C)F(59,63,C)
#define P_M7(F,C) F(0,7,C)F(1,6,C)F(2,5,C)F(3,4,C)F(8,15,C)F(9,14,C)F(10,13,C)F(11,12,C)F(16,23,C)F(17,22,C)F(18,21,C)F(19,20,C)F(24,31,C)F(25,30,C)F(26,29,C)F(27,28,C)F(32,39,C)F(33,38,C)F(34,37,C)F(35,36,C)F(40,47,C)F(41,46,C)F(42,45,C)F(43,44,C)F(48,55,C)F(49,54,C)F(50,53,C)F(51,52,C)F(56,63,C)F(57,62,C)F(58,61,C)F(59,60,C)
#define P_M8(F,C) F(0,8,C)F(1,9,C)F(2,10,C)F(3,11,C)F(4,12,C)F(5,13,C)F(6,14,C)F(7,15,C)F(16,24,C)F(17,25,C)F(18,26,C)F(19,27,C)F(20,28,C)F(21,29,C)F(22,30,C)F(23,31,C)F(32,40,C)F(33,41,C)F(34,42,C)F(35,43,C)F(36,44,C)F(37,45,C)F(38,46,C)F(39,47,C)F(48,56,C)F(49,57,C)F(50,58,C)F(51,59,C)F(52,60,C)F(53,61,C)F(54,62,C)F(55,63,C)
#define P_M15(F,C) F(0,15,C)F(1,14,C)F(2,13,C)F(3,12,C)F(4,11,C)F(5,10,C)F(6,9,C)F(7,8,C)F(16,31,C)F(17,30,C)F(18,29,C)F(19,28,C)F(20,27,C)F(21,26,C)F(22,25,C)F(23,24,C)F(32,47,C)F(33,46,C)F(34,45,C)F(35,44,C)F(36,43,C)F(37,42,C)F(38,41,C)F(39,40,C)F(48,63,C)F(49,62,C)F(50,61,C)F(51,60,C)F(52,59,C)F(53,58,C)F(54,57,C)F(55,56,C)
#define P_M16(F,C) F(0,16,C)F(1,17,C)F(2,18,C)F(3,19,C)F(4,20,C)F(5,21,C)F(6,22,C)F(7,23,C)F(8,24,C)F(9,25,C)F(10,26,C)F(11,27,C)F(12,28,C)F(13,29,C)F(14,30,C)F(15,31,C)F(32,48,C)F(33,49,C)F(34,50,C)F(35,51,C)F(36,52,C)F(37,53,C)F(38,54,C)F(39,55,C)F(40,56,C)F(41,57,C)F(42,58,C)F(43,59,C)F(44,60,C)F(45,61,C)F(46,62,C)F(47,63,C)
#define P_M31(F,C) F(0,31,C)F(1,30,C)F(2,29,C)F(3,28,C)F(4,27,C)F(5,26,C)F(6,25,C)F(7,24,C)F(8,23,C)F(9,22,C)F(10,21,C)F(11,20,C)F(12,19,C)F(13,18,C)F(14,17,C)F(15,16,C)F(32,63,C)F(33,62,C)F(34,61,C)F(35,60,C)F(36,59,C)F(37,58,C)F(38,57,C)F(39,56,C)F(40,55,C)F(41,54,C)F(42,53,C)F(43,52,C)F(44,51,C)F(45,50,C)F(46,49,C)F(47,48,C)
#define P_M32(F,C) F(0,32,C)F(1,33,C)F(2,34,C)F(3,35,C)F(4,36,C)F(5,37,C)F(6,38,C)F(7,39,C)F(8,40,C)F(9,41,C)F(10,42,C)F(11,43,C)F(12,44,C)F(13,45,C)F(14,46,C)F(15,47,C)F(16,48,C)F(17,49,C)F(18,50,C)F(19,51,C)F(20,52,C)F(21,53,C)F(22,54,C)F(23,55,C)F(24,56,C)F(25,57,C)F(26,58,C)F(27,59,C)F(28,60,C)F(29,61,C)F(30,62,C)F(31,63,C)
#define P_M63(F,C) F(0,63,C)F(1,62,C)F(2,61,C)F(3,60,C)F(4,59,C)F(5,58,C)F(6,57,C)F(7,56,C)F(8,55,C)F(9,54,C)F(10,53,C)F(11,52,C)F(12,51,C)F(13,50,C)F(14,49,C)F(15,48,C)F(16,47,C)F(17,46,C)F(18,45,C)F(19,44,C)F(20,43,C)F(21,42,C)F(22,41,C)F(23,40,C)F(24,39,C)F(25,38,C)F(26,37,C)F(27,36,C)F(28,35,C)F(29,34,C)F(30,33,C)F(31,32,C)

#define CLEAN6 P_M32(CEP,0) P_M16(CEP,0) P_M8(CEP,0) P_M4(CEP,0) P_M2(CEP,0) P_M1(CEP,0)

#define LOADQ(q,E0,E1,E2,E3,E4,E5,E6,E7) { uint4 x0_ = c0[q], x1_ = c1[q]; \
  a##E0 = (int)((x0_.x & 0xffffu) | (x1_.x << 16)); a##E1 = (int)((x0_.x >> 16) | (x1_.x & 0xffff0000u)); \
  a##E2 = (int)((x0_.y & 0xffffu) | (x1_.y << 16)); a##E3 = (int)((x0_.y >> 16) | (x1_.y & 0xffff0000u)); \
  a##E4 = (int)((x0_.z & 0xffffu) | (x1_.z << 16)); a##E5 = (int)((x0_.z >> 16) | (x1_.z & 0xffff0000u)); \
  a##E6 = (int)((x0_.w & 0xffffu) | (x1_.w << 16)); a##E7 = (int)((x0_.w >> 16) | (x1_.w & 0xffff0000u)); }

#define POOLQ(q,E0,E1,E2,E3) { float4 w0_ = pw0[q], w1_ = pw1[q]; h2 v_; \
  v_ = ih2(a##E0); s0 = fmaf((float)v_[0], w0_.x, s0); s1 = fmaf((float)v_[1], w1_.x, s1); \
  v_ = ih2(a##E1); s0 = fmaf((float)v_[0], w0_.y, s0); s1 = fmaf((float)v_[1], w1_.y, s1); \
  v_ = ih2(a##E2); s0 = fmaf((float)v_[0], w0_.z, s0); s1 = fmaf((float)v_[1], w1_.z, s1); \
  v_ = ih2(a##E3); s0 = fmaf((float)v_[0], w0_.w, s0); s1 = fmaf((float)v_[1], w1_.w, s1); }

__global__ __launch_bounds__(64, 2) void k_sortpool(const unsigned short* __restrict__ yt,
                                                    const float* __restrict__ pwt,
                                                    float* __restrict__ out) {
  int t = threadIdx.x;  // lane 0..63 (one wave per block)
  int b = blockIdx.x >> 7, p = blockIdx.x & 127;
  int o0 = p * 2, o1 = o0 + 1;
  const uint4* c0 = (const uint4*)(yt + (size_t)(b * 256 + o0) * 4096 + t * 64);
  const uint4* c1 = (const uint4*)(yt + (size_t)(b * 256 + o1) * 4096 + t * 64);
  int a0,a1,a2,a3,a4,a5,a6,a7,a8,a9,a10,a11,a12,a13,a14,a15,
      a16,a17,a18,a19,a20,a21,a22,a23,a24,a25,a26,a27,a28,a29,a30,a31,
      a32,a33,a34,a35,a36,a37,a38,a39,a40,a41,a42,a43,a44,a45,a46,a47,
      a48,a49,a50,a51,a52,a53,a54,a55,a56,a57,a58,a59,a60,a61,a62,a63;
  LOADQ(0, 0,1,2,3,4,5,6,7)
  LOADQ(1, 8,9,10,11,12,13,14,15)
  LOADQ(2, 16,17,18,19,20,21,22,23)
  LOADQ(3, 24,25,26,27,28,29,30,31)
  LOADQ(4, 32,33,34,35,36,37,38,39)
  LOADQ(5, 40,41,42,43,44,45,46,47)
  LOADQ(6, 48,49,50,51,52,53,54,55)
  LOADQ(7, 56,57,58,59,60,61,62,63)
  // stages s1..s6 (runs <= 64): pure in-register
  P_M1(CEP,0)
  P_M3(CEP,0) P_M1(CEP,0)
  P_M7(CEP,0) P_M2(CEP,0) P_M1(CEP,0)
  P_M15(CEP,0) P_M4(CEP,0) P_M2(CEP,0) P_M1(CEP,0)
  P_M31(CEP,0) P_M8(CEP,0) P_M4(CEP,0) P_M2(CEP,0) P_M1(CEP,0)
  P_M63(CEP,0) P_M16(CEP,0) P_M8(CEP,0) P_M4(CEP,0) P_M2(CEP,0) P_M1(CEP,0)
  // s7 -> 128-runs
  { const bool km_ = !(t & 1); P_M63(KFD, DPP_X1) } CLEAN6
  // s8 -> 256
  { const bool km_ = !(t & 2); P_M63(KFD, DPP_X3) }
  { const bool km_ = !(t & 1); L64(KC, DPP_X1) } CLEAN6
  // s9 -> 512
  { const bool km_ = !(t & 4); P_M63(KFD, DPP_X7) }
  { const bool km_ = !(t & 2); L64(KC, DPP_X2) }
  { const bool km_ = !(t & 1); L64(KC, DPP_X1) } CLEAN6
  // s10 -> 1024
  { const bool km_ = !(t & 8); P_M63(KFD, DPP_XF) }
  { const bool km_ = !(t & 4); const int pa_ = ((t ^ 4) & 63) << 2; L64(KB, 0) }
  { const bool km_ = !(t & 2); L64(KC, DPP_X2) }
  { const bool km_ = !(t & 1); L64(KC, DPP_X1) } CLEAN6
  // s11 -> 2048
  { const bool km_ = !(t & 16); const int pa_ = ((t ^ 31) & 63) << 2; P_M63(KFB, 0) }
  { const bool km_ = !(t & 8); L64(KC, DPP_X8) }
  { const bool km_ = !(t & 4); const int pa_ = ((t ^ 4) & 63) << 2; L64(KB, 0) }
  { const bool km_ = !(t & 2); L64(KC, DPP_X2) }
  { const bool km_ = !(t & 1); L64(KC, DPP_X1) } CLEAN6
  // s12 -> 4096
  { const bool km_ = !(t & 32); const int pa_ = ((t ^ 63) & 63) << 2; P_M63(KFB, 0) }
  { const bool km_ = !(t & 16); const int pa_ = ((t ^ 16) & 63) << 2; L64(KB, 0) }
  { const bool km_ = !(t & 8); L64(KC, DPP_X8) }
  { const bool km_ = !(t & 4); const int pa_ = ((t ^ 4) & 63) << 2; L64(KB, 0) }
  { const bool km_ = !(t & 2); L64(KC, DPP_X2) }
  { const bool km_ = !(t & 1); L64(KC, DPP_X1) } CLEAN6
  // rank-weighted sum: rank of a{e} is 64t+e; lo half -> o0, hi half -> o1
  const float4* pw0 = (const float4*)(pwt + (size_t)o0 * 4096 + t * 64);
  const float4* pw1 = (const float4*)(pwt + (size_t)o1 * 4096 + t * 64);
  float s0 = 0.f, s1 = 0.f;
  POOLQ(0, 0,1,2,3)   POOLQ(1, 4,5,6,7)   POOLQ(2, 8,9,10,11)  POOLQ(3, 12,13,14,15)
  POOLQ(4, 16,17,18,19) POOLQ(5, 20,21,22,23) POOLQ(6, 24,25,26,27) POOLQ(7, 28,29,30,31)
  POOLQ(8, 32,33,34,35) POOLQ(9, 36,37,38,39) POOLQ(10, 40,41,42,43) POOLQ(11, 44,45,46,47)
  POOLQ(12, 48,49,50,51) POOLQ(13, 52,53,54,55) POOLQ(14, 56,57,58,59) POOLQ(15, 60,61,62,63)
#pragma unroll
  for (int off = 32; off > 0; off >>= 1) {
    s0 += __shfl_xor(s0, off);
    s1 += __shfl_xor(s1, off);
  }
  if (t == 0) {
    out[b * 256 + o0] = s0;
    out[b * 256 + o1] = s1;
  }
}

extern "C" void kernel_launch(void* const* d_in, const int* in_sizes, int n_in,
                              void* d_out, int out_size, void* d_ws, size_t ws_size,
                              hipStream_t stream) {
  const float* x  = (const float*)d_in[0];
  const float* w1 = (const float*)d_in[1];
  const float* b1 = (const float*)d_in[2];
  const float* w2 = (const float*)d_in[3];
  const float* b2 = (const float*)d_in[4];
  const float* pw = (const float*)d_in[5];
  char* ws = (char*)d_ws;
  _Float16* u   = (_Float16*)ws;                                   // 2 MiB
  _Float16* v   = (_Float16*)(ws + (2u << 20));                    // 2 MiB
  _Float16* w2t = (_Float16*)(ws + (4u << 20));                    // 256 KiB
  float*    pwt = (float*)(ws + (5u << 20));                       // 4 MiB
  unsigned short* yt = (unsigned short*)(ws + (9u << 20));         // 64 MiB f16
  float* out = (float*)d_out;

  k_prep<<<dim3(768), dim3(256), 0, stream>>>(x, w1, b1, w2, pw, u, v, w2t, pwt);
  k_gemm<<<dim3(512), dim3(256), 0, stream>>>(u, v, w2t, b2, yt);
  k_sortpool<<<dim3(4096), dim3(64), 0, stream>>>(yt, pwt, out);
}